// Round 1
// baseline (464.472 us; speedup 1.0000x reference)
//
#include <hip/hip_runtime.h>
#include <stdint.h>
#include <math.h>

// ---------------- problem constants ----------------
#define S_LEN 4096
#define BATCH 4
#define DIM   1024
#define AP    256
#define NBLK  32            // S_LEN/128 row-blocks per batch
#define BANDC 640           // 5*128 band columns
#define SCALE 0.03125f      // 1/sqrt(1024)

typedef __attribute__((ext_vector_type(4))) float f32x4;
typedef __attribute__((ext_vector_type(8))) short bf16x8;

// ---------------- helpers ----------------
__device__ __forceinline__ ushort f2bf(float f) {
  union { float f; uint32_t u; } v; v.f = f;
  uint32_t r = v.u + 0x7FFFu + ((v.u >> 16) & 1u);
  return (ushort)(r >> 16);
}

__device__ __forceinline__ void gload16(const void* g, void* l) {
  __builtin_amdgcn_global_load_lds((const __attribute__((address_space(1))) void*)g,
                                   (__attribute__((address_space(3))) void*)l,
                                   16, 0, 0);
}

__device__ __forceinline__ float block_sum(float v, float* red) {
  #pragma unroll
  for (int o = 32; o > 0; o >>= 1) v += __shfl_xor(v, o, 64);
  const int w = threadIdx.x >> 6;
  if ((threadIdx.x & 63) == 0) red[w] = v;
  __syncthreads();
  v = red[0] + red[1] + red[2] + red[3];
  __syncthreads();
  return v;
}

__device__ __forceinline__ float block_max(float v, float* red) {
  #pragma unroll
  for (int o = 32; o > 0; o >>= 1) v = fmaxf(v, __shfl_xor(v, o, 64));
  const int w = threadIdx.x >> 6;
  if ((threadIdx.x & 63) == 0) red[w] = v;
  __syncthreads();
  v = fmaxf(fmaxf(red[0], red[1]), fmaxf(red[2], red[3]));
  __syncthreads();
  return v;
}

// ---------------- GEMM core: 128x128 tile, BK=32, 4 waves, B^T operand ----------------
// A: row-major [128 rows x K], lda elems. B: row-major [128 "n" rows x K] (i.e. B^T), ldb elems.
// acc[m][n] holds the wave's 4x4 grid of 16x16 fragments.
__device__ __forceinline__ void gemm_core(
    const ushort* __restrict__ Ablk, int lda,
    const ushort* __restrict__ Bblk, int ldb,
    int k_begin, int k_end,
    ushort* __restrict__ As, ushort* __restrict__ Bs,
    f32x4 acc[4][4])
{
  const int tid  = threadIdx.x;
  const int lane = tid & 63;
  const int wr = ((tid >> 7) & 1) * 64;
  const int wc = ((tid >> 6) & 1) * 64;
  const int lr = lane & 15;
  const int ks = (lane >> 4) << 3;

  const int row0 = tid >> 2;
  const int row1 = 64 + row0;
  const int seg  = tid & 3;
  ushort* ldsA0 = As + (tid & 192) * 8;
  ushort* ldsA1 = As + (256 + (tid & 192)) * 8;
  ushort* ldsB0 = Bs + (tid & 192) * 8;
  ushort* ldsB1 = Bs + (256 + (tid & 192)) * 8;

  for (int k0 = k_begin; k0 < k_end; k0 += 32) {
    __syncthreads();
    gload16(Ablk + (size_t)row0 * lda + k0 + seg * 8, ldsA0);
    gload16(Ablk + (size_t)row1 * lda + k0 + seg * 8, ldsA1);
    gload16(Bblk + (size_t)row0 * ldb + k0 + seg * 8, ldsB0);
    gload16(Bblk + (size_t)row1 * ldb + k0 + seg * 8, ldsB1);
    asm volatile("s_waitcnt vmcnt(0)" ::: "memory");
    __syncthreads();

    bf16x8 af[4], bfv[4];
    #pragma unroll
    for (int m = 0; m < 4; m++)
      af[m] = *(const bf16x8*)(As + (wr + m * 16 + lr) * 32 + ks);
    #pragma unroll
    for (int n = 0; n < 4; n++)
      bfv[n] = *(const bf16x8*)(Bs + (wc + n * 16 + lr) * 32 + ks);
    #pragma unroll
    for (int m = 0; m < 4; m++)
      #pragma unroll
      for (int n = 0; n < 4; n++)
        acc[m][n] = __builtin_amdgcn_mfma_f32_16x16x32_bf16(af[m], bfv[n], acc[m][n], 0, 0, 0);
  }
}

#define ACC_ZERO(acc) \
  _Pragma("unroll") for (int m_ = 0; m_ < 4; m_++) \
  _Pragma("unroll") for (int n_ = 0; n_ < 4; n_++) \
  _Pragma("unroll") for (int r_ = 0; r_ < 4; r_++) acc[m_][n_][r_] = 0.0f;

#define EPI_BEGIN(acc) { \
  const int lane_ = threadIdx.x & 63; \
  const int wr_ = ((threadIdx.x >> 7) & 1) * 64; \
  const int wc_ = ((threadIdx.x >> 6) & 1) * 64; \
  const int rb_ = (lane_ >> 4) << 2; \
  const int cb_ = lane_ & 15; \
  _Pragma("unroll") for (int m_ = 0; m_ < 4; m_++) \
  _Pragma("unroll") for (int n_ = 0; n_ < 4; n_++) \
  _Pragma("unroll") for (int r_ = 0; r_ < 4; r_++) { \
    const int rloc = wr_ + m_ * 16 + rb_ + r_; \
    const int cloc = wc_ + n_ * 16 + cb_; \
    const float aval = acc[m_][n_][r_];
#define EPI_END() } }

// ---------------- kernels ----------------
__global__ __launch_bounds__(256) void prep_x(const float* __restrict__ x, ushort* __restrict__ xb) {
  size_t idx = ((size_t)blockIdx.x * 256 + threadIdx.x) * 4;   // dest flat index (b,s,d)
  int d = (int)(idx & 1023);
  int s = (int)((idx >> 10) & 4095);
  int b = (int)(idx >> 22);
  float4 v = *(const float4*)(x + ((size_t)s * BATCH + b) * DIM + d);
  ushort4 o;
  o.x = f2bf(v.x); o.y = f2bf(v.y); o.z = f2bf(v.z); o.w = f2bf(v.w);
  *(ushort4*)(xb + idx) = o;
}

__global__ __launch_bounds__(256) void f2bf_vec(const float* __restrict__ src, ushort* __restrict__ dst, int n) {
  int idx = (blockIdx.x * 256 + threadIdx.x) * 4;
  if (idx >= n) return;
  float4 v = *(const float4*)(src + idx);
  ushort4 o;
  o.x = f2bf(v.x); o.y = f2bf(v.y); o.z = f2bf(v.z); o.w = f2bf(v.w);
  *(ushort4*)(dst + idx) = o;
}

// out[col-block]: 0..7 -> K, 8..15 -> Q, 16..23 -> V   (wqkv packed rows [Wk;Wq;Wv])
__global__ __launch_bounds__(256) void qkv_gemm(
    const ushort* __restrict__ xb, const ushort* __restrict__ wqkv,
    ushort* __restrict__ Kp, ushort* __restrict__ Qp, ushort* __restrict__ Vp)
{
  __shared__ ushort As[4096], Bs[4096];
  const int by = blockIdx.y;   // 0..127  (128 rows each)
  const int bx = blockIdx.x;   // 0..23
  f32x4 acc[4][4];
  ACC_ZERO(acc)
  gemm_core(xb + (size_t)by * 128 * DIM, DIM,
            wqkv + (size_t)bx * 128 * DIM, DIM, 0, DIM, As, Bs, acc);
  ushort* dst = (bx < 8) ? Kp : (bx < 16) ? Qp : Vp;
  const int colb = (bx & 7) * 128;
  EPI_BEGIN(acc)
    int row = by * 128 + rloc;
    int col = colb + cloc;
    dst[(size_t)row * DIM + col] = f2bf(aval);
  EPI_END()
}

__global__ __launch_bounds__(256) void transpose_v(const ushort* __restrict__ V, ushort* __restrict__ VT) {
  __shared__ ushort tile[64][66];
  const int s0 = blockIdx.x * 64, d0 = blockIdx.y * 64, b = blockIdx.z;
  const ushort* Vb = V + (size_t)b * S_LEN * DIM;
  ushort* VTb = VT + (size_t)b * DIM * S_LEN;
  #pragma unroll
  for (int it = 0; it < 16; it++) {
    int flat = it * 256 + threadIdx.x;
    int r = flat >> 6, c = flat & 63;
    tile[r][c] = Vb[(size_t)(s0 + r) * DIM + d0 + c];
  }
  __syncthreads();
  #pragma unroll
  for (int it = 0; it < 16; it++) {
    int flat = it * 256 + threadIdx.x;
    int r = flat >> 6, c = flat & 63;      // r = d-local, c = s-local
    VTb[(size_t)(d0 + r) * S_LEN + s0 + c] = tile[c][r];
  }
}

__global__ __launch_bounds__(256) void scores_gemm(
    const ushort* __restrict__ Qp, const ushort* __restrict__ Kp,
    float* __restrict__ eband)
{
  const int bid = blockIdx.x;        // 4*32*5 = 640
  const int b   = bid / 160;
  const int rem = bid % 160;
  const int i   = rem / 5;
  const int jj  = rem % 5;
  const int j   = i - 2 + jj;
  if (j < 0 || j >= NBLK) return;
  __shared__ ushort As[4096], Bs[4096];
  f32x4 acc[4][4];
  ACC_ZERO(acc)
  gemm_core(Qp + ((size_t)b * S_LEN + i * 128) * DIM, DIM,
            Kp + ((size_t)b * S_LEN + j * 128) * DIM, DIM, 0, DIM, As, Bs, acc);
  EPI_BEGIN(acc)
    int q = i * 128 + rloc;
    int k = j * 128 + cloc;
    float v = aval * SCALE;
    int dqk = q - k;
    if (dqk == 0 || dqk > AP || dqk < -AP) v = -INFINITY;
    eband[((size_t)b * S_LEN + q) * BANDC + jj * 128 + cloc] = v;
  EPI_END()
}

__global__ __launch_bounds__(256) void softmax_band(const float* __restrict__ eband,
                                                    ushort* __restrict__ aband)
{
  __shared__ float red[4];
  const int qg = blockIdx.x;          // 0..16383
  const int s  = qg & 4095;
  const int i  = s >> 7;
  const float* row = eband + (size_t)qg * BANDC;
  ushort* arow = aband + (size_t)qg * BANDC;

  float vals[3];
  bool  valid[3];
  float mx = -INFINITY;
  #pragma unroll
  for (int t = 0; t < 3; t++) {
    int idx = threadIdx.x + t * 256;
    int jj = idx >> 7;
    int j = i - 2 + jj;
    bool ok = (idx < BANDC) && (j >= 0) && (j < NBLK);
    valid[t] = ok;
    float v = ok ? row[idx] : -INFINITY;
    vals[t] = v;
    mx = fmaxf(mx, v);
  }
  float bmax = block_max(mx, red);
  float ss = 0.0f;
  #pragma unroll
  for (int t = 0; t < 3; t++) {
    float e = valid[t] ? __expf(vals[t] - bmax) : 0.0f;
    vals[t] = e;
    ss += e;
  }
  float inv = 1.0f / block_sum(ss, red);
  #pragma unroll
  for (int t = 0; t < 3; t++) {
    int idx = threadIdx.x + t * 256;
    if (idx < BANDC) arow[idx] = f2bf(vals[t] * inv);
  }
}

__global__ __launch_bounds__(256) void av_gemm(
    const ushort* __restrict__ aband, const ushort* __restrict__ VT,
    ushort* __restrict__ cbuf)
{
  const int by = blockIdx.y;          // 0..127: (b,i)
  const int b = by >> 5, i = by & 31;
  const int bx = blockIdx.x;          // 0..7 d-block
  const int jj_lo = (i < 2) ? (2 - i) : 0;
  const int jj_hi = (i > 29) ? (34 - i) : 5;
  __shared__ ushort As[4096], Bs[4096];
  f32x4 acc[4][4];
  ACC_ZERO(acc)
  const ushort* Ablk = aband + ((size_t)b * S_LEN + i * 128) * BANDC;
  const ushort* Bblk = VT + (size_t)b * DIM * S_LEN + (size_t)bx * 128 * S_LEN + (i - 2) * 128;
  gemm_core(Ablk, BANDC, Bblk, S_LEN, jj_lo * 128, jj_hi * 128, As, Bs, acc);
  EPI_BEGIN(acc)
    int row = b * S_LEN + i * 128 + rloc;
    int col = bx * 128 + cloc;
    cbuf[(size_t)row * DIM + col] = f2bf(aval);
  EPI_END()
}

__global__ __launch_bounds__(256) void wp_gemm(
    const ushort* __restrict__ cbuf, const ushort* __restrict__ wpb,
    const float* __restrict__ x, float* __restrict__ y0)
{
  __shared__ ushort As[4096], Bs[4096];
  const int by = blockIdx.y;   // 0..127
  const int bx = blockIdx.x;   // 0..7
  f32x4 acc[4][4];
  ACC_ZERO(acc)
  gemm_core(cbuf + (size_t)by * 128 * DIM, DIM,
            wpb + (size_t)bx * 128 * DIM, DIM, 0, DIM, As, Bs, acc);
  EPI_BEGIN(acc)
    int row = by * 128 + rloc;           // b*4096+s
    int col = bx * 128 + cloc;
    int b = row >> 12, s = row & 4095;
    float v = aval + x[((size_t)s * BATCH + b) * DIM + col];
    y0[(size_t)row * DIM + col] = v;
  EPI_END()
}

__global__ __launch_bounds__(256) void ln_kernel(const float* __restrict__ y0, ushort* __restrict__ y1,
                                                 const float* __restrict__ gamma, const float* __restrict__ beta)
{
  __shared__ float red[4];
  const size_t q = blockIdx.x;
  const float* row = y0 + q * DIM;
  float v[4];
  #pragma unroll
  for (int t = 0; t < 4; t++) v[t] = row[threadIdx.x + t * 256];
  float mean = block_sum(v[0] + v[1] + v[2] + v[3], red) * (1.0f / DIM);
  float q2 = 0.0f;
  #pragma unroll
  for (int t = 0; t < 4; t++) { float d = v[t] - mean; q2 += d * d; }
  float var = block_sum(q2, red) * (1.0f / DIM);
  float rstd = rsqrtf(var + 1e-6f);
  #pragma unroll
  for (int t = 0; t < 4; t++) {
    int d = threadIdx.x + t * 256;
    y1[q * DIM + d] = f2bf((v[t] - mean) * rstd * gamma[d] + beta[d]);
  }
}

__global__ __launch_bounds__(256) void ffn1_gemm(
    const ushort* __restrict__ y1, const ushort* __restrict__ w1b,
    const float* __restrict__ b1, float* __restrict__ h0)
{
  __shared__ ushort As[4096], Bs[4096];
  const int by = blockIdx.y;
  const int bx = blockIdx.x;
  f32x4 acc[4][4];
  ACC_ZERO(acc)
  gemm_core(y1 + (size_t)by * 128 * DIM, DIM,
            w1b + (size_t)bx * 128 * DIM, DIM, 0, DIM, As, Bs, acc);
  EPI_BEGIN(acc)
    int row = by * 128 + rloc;
    int col = bx * 128 + cloc;
    float v = aval + b1[col];
    h0[(size_t)row * DIM + col] = fmaxf(v, 0.0f);
  EPI_END()
}

__global__ __launch_bounds__(256) void head_kernel(const float* __restrict__ h0,
    const float* __restrict__ gamma, const float* __restrict__ beta,
    const float* __restrict__ W2, const float* __restrict__ b2,
    float* __restrict__ out)
{
  __shared__ float red[4];
  const int qg = blockIdx.x;
  const int b = qg >> 12, s = qg & 4095;
  const float* row = h0 + (size_t)qg * DIM;
  float v[4];
  #pragma unroll
  for (int t = 0; t < 4; t++) v[t] = row[threadIdx.x + t * 256];
  float mean = block_sum(v[0] + v[1] + v[2] + v[3], red) * (1.0f / DIM);
  float q2 = 0.0f;
  #pragma unroll
  for (int t = 0; t < 4; t++) { float d = v[t] - mean; q2 += d * d; }
  float var = block_sum(q2, red) * (1.0f / DIM);
  float rstd = rsqrtf(var + 1e-6f);
  float part = 0.0f;
  #pragma unroll
  for (int t = 0; t < 4; t++) {
    int d = threadIdx.x + t * 256;
    part += ((v[t] - mean) * rstd * gamma[d] + beta[d]) * W2[d];
  }
  float logit = block_sum(part, red) + b2[0];
  if (threadIdx.x == 0) out[(size_t)s * BATCH + b] = 1.0f / (1.0f + expf(-logit));
}

// ---------------- launch ----------------
extern "C" void kernel_launch(void* const* d_in, const int* in_sizes, int n_in,
                              void* d_out, int out_size, void* d_ws, size_t ws_size,
                              hipStream_t stream) {
  const float* x     = (const float*)d_in[0];
  const float* Wk    = (const float*)d_in[1];
  const float* Wq    = (const float*)d_in[2];
  const float* Wv    = (const float*)d_in[3];
  const float* Wp    = (const float*)d_in[4];
  const float* W1    = (const float*)d_in[5];
  const float* b1    = (const float*)d_in[6];
  const float* W2    = (const float*)d_in[7];
  const float* b2    = (const float*)d_in[8];
  const float* gamma = (const float*)d_in[9];
  const float* beta  = (const float*)d_in[10];
  float* out = (float*)d_out;

  char* w = (char*)d_ws;
  ushort* xb   = (ushort*)(w + 0);            // 33,554,432 B
  ushort* wqkv = (ushort*)(w + 33554432);     //  6,291,456 B
  ushort* wpb  = (ushort*)(w + 39845888);     //  2,097,152 B
  ushort* w1b  = (ushort*)(w + 41943040);     //  2,097,152 B
  ushort* Qp   = (ushort*)(w + 44040192);     // 33,554,432 B
  ushort* Kp   = (ushort*)(w + 77594624);     // 33,554,432 B
  ushort* Vp   = (ushort*)(w + 111149056);    // 33,554,432 B
  ushort* VT   = (ushort*)(w + 144703488);    // 33,554,432 B
  float*  big  = (float*)(w + 178257920);     // 67,108,864 B (eband -> y0 -> h0)
  // reuse (sequentially dead regions):
  ushort* aband = Qp;     // 20,971,520 B needed, Q dead after scores
  ushort* cbuf  = Kp;     // K dead after scores
  ushort* y1    = Vp;     // V dead after transpose
  float* eband = big;
  float* y0    = big;
  float* h0    = big;

  prep_x<<<16384, 256, 0, stream>>>(x, xb);
  f2bf_vec<<<1024, 256, 0, stream>>>(Wk, wqkv,            1048576);
  f2bf_vec<<<1024, 256, 0, stream>>>(Wq, wqkv + 1048576,  1048576);
  f2bf_vec<<<1024, 256, 0, stream>>>(Wv, wqkv + 2097152,  1048576);
  f2bf_vec<<<1024, 256, 0, stream>>>(Wp, wpb, 1048576);
  f2bf_vec<<<1024, 256, 0, stream>>>(W1, w1b, 1048576);

  qkv_gemm<<<dim3(24, 128), 256, 0, stream>>>(xb, wqkv, Kp, Qp, Vp);
  transpose_v<<<dim3(64, 16, 4), 256, 0, stream>>>(Vp, VT);
  scores_gemm<<<640, 256, 0, stream>>>(Qp, Kp, eband);
  softmax_band<<<16384, 256, 0, stream>>>(eband, aband);
  av_gemm<<<dim3(8, 128), 256, 0, stream>>>(aband, VT, cbuf);
  wp_gemm<<<dim3(8, 128), 256, 0, stream>>>(cbuf, wpb, x, y0);
  ln_kernel<<<16384, 256, 0, stream>>>(y0, y1, gamma, beta);
  ffn1_gemm<<<dim3(8, 128), 256, 0, stream>>>(y1, w1b, b1, h0);
  head_kernel<<<16384, 256, 0, stream>>>(h0, gamma, beta, W2, b2, out);
}

// Round 2
// 421.429 us; speedup vs baseline: 1.1021x; 1.1021x over previous
//
#include <hip/hip_runtime.h>
#include <stdint.h>
#include <math.h>

// ---------------- problem constants ----------------
#define S_LEN 4096
#define BATCH 4
#define DIM   1024
#define AP    256
#define NBLK  32            // S_LEN/128 row-blocks per batch
#define BANDC 640           // 5*128 band columns
#define SCALE 0.03125f      // 1/sqrt(1024)

typedef __attribute__((ext_vector_type(4))) float f32x4;
typedef __attribute__((ext_vector_type(8))) short bf16x8;

// ---------------- helpers ----------------
__device__ __forceinline__ ushort f2bf(float f) {
  union { float f; uint32_t u; } v; v.f = f;
  uint32_t r = v.u + 0x7FFFu + ((v.u >> 16) & 1u);
  return (ushort)(r >> 16);
}

__device__ __forceinline__ void gload16(const void* g, void* l) {
  __builtin_amdgcn_global_load_lds((const __attribute__((address_space(1))) void*)g,
                                   (__attribute__((address_space(3))) void*)l,
                                   16, 0, 0);
}

__device__ __forceinline__ float block_sum(float v, float* red) {
  #pragma unroll
  for (int o = 32; o > 0; o >>= 1) v += __shfl_xor(v, o, 64);
  const int w = threadIdx.x >> 6;
  if ((threadIdx.x & 63) == 0) red[w] = v;
  __syncthreads();
  v = red[0] + red[1] + red[2] + red[3];
  __syncthreads();
  return v;
}

__device__ __forceinline__ float block_max(float v, float* red) {
  #pragma unroll
  for (int o = 32; o > 0; o >>= 1) v = fmaxf(v, __shfl_xor(v, o, 64));
  const int w = threadIdx.x >> 6;
  if ((threadIdx.x & 63) == 0) red[w] = v;
  __syncthreads();
  v = fmaxf(fmaxf(red[0], red[1]), fmaxf(red[2], red[3]));
  __syncthreads();
  return v;
}

// =====================================================================
// 256x256 pipelined GEMM core (T2+T3+T4+T5):
//  - 512 threads = 8 waves (2 wave-rows x 4 wave-cols), per-wave C = 128x64
//  - BK=32, 4 LDS K-tile buffers (A 16KB + B 16KB each) = 128 KiB
//  - depth-3 prefetch, counted vmcnt(8) steady state, ONE s_barrier/K-step
//  - XOR seg-swizzle: LDS slot (row,seg) holds global seg^(row&3)
//    write side linear (global_load_lds), source pre-swizzled, read swizzled
// A: row-major [256 x K] (lda), B: row-major [256 "n-rows" x K] (ldb) = B^T
// Requires K % 32 == 0 and K >= 96.
// =====================================================================
__device__ __forceinline__ void gemm256_core(
    const ushort* __restrict__ Ablk, int lda,
    const ushort* __restrict__ Bblk, int ldb,
    int K, ushort* __restrict__ lds,
    f32x4 acc[8][4])
{
  const int tid  = threadIdx.x;
  const int lane = tid & 63;
  const int wave = tid >> 6;
  const int wr = wave >> 2;       // 0..1
  const int wn = wave & 3;        // 0..3

  // ---- staging addresses (pre-swizzled global source, linear LDS dest) ----
  const int srow = tid >> 2;                       // 0..127
  const int gseg = (tid & 3) ^ (srow & 3);
  const ushort* gA0 = Ablk + (size_t)srow * lda + gseg * 8;
  const ushort* gA1 = Ablk + (size_t)(srow + 128) * lda + gseg * 8;
  const ushort* gB0 = Bblk + (size_t)srow * ldb + gseg * 8;
  const ushort* gB1 = Bblk + (size_t)(srow + 128) * ldb + gseg * 8;
  const int stA = wave * 512;                      // wave-uniform LDS base (ushorts)

  // ---- swizzled ds_read addresses ----
  const int l15 = lane & 15;
  const int seg = (lane >> 4) ^ (lane & 3);        // (row&3) == (lane&3) since 16|frag row base
  const int roffA = (wr * 128 + l15) * 32 + seg * 8;   // + m*512
  const int roffB = (wn * 64  + l15) * 32 + seg * 8;   // + n*512

  const int NT = K >> 5;

  // ---- prologue: stage tiles 0..2 ----
  #pragma unroll
  for (int p = 0; p < 3; ++p) {
    ushort* buf = lds + p * 16384;
    const int k0 = p * 32;
    gload16(gA0 + k0, buf + stA);
    gload16(gA1 + k0, buf + 4096  + stA);
    gload16(gB0 + k0, buf + 8192  + stA);
    gload16(gB1 + k0, buf + 12288 + stA);
  }

  for (int t = 0; t < NT; ++t) {
    const int rem = NT - 1 - t;
    if (rem >= 2)      asm volatile("s_waitcnt vmcnt(8)" ::: "memory");
    else if (rem == 1) asm volatile("s_waitcnt vmcnt(4)" ::: "memory");
    else               asm volatile("s_waitcnt vmcnt(0)" ::: "memory");
    __builtin_amdgcn_s_barrier();

    if (t + 3 < NT) {
      ushort* buf = lds + ((t + 3) & 3) * 16384;
      const int k0 = (t + 3) * 32;
      gload16(gA0 + k0, buf + stA);
      gload16(gA1 + k0, buf + 4096  + stA);
      gload16(gB0 + k0, buf + 8192  + stA);
      gload16(gB1 + k0, buf + 12288 + stA);
    }

    const ushort* buf = lds + (t & 3) * 16384;
    bf16x8 af[8], bfv[4];
    #pragma unroll
    for (int m = 0; m < 8; ++m) af[m] = *(const bf16x8*)(buf + roffA + m * 512);
    #pragma unroll
    for (int n = 0; n < 4; ++n) bfv[n] = *(const bf16x8*)(buf + 8192 + roffB + n * 512);

    __builtin_amdgcn_s_setprio(1);
    #pragma unroll
    for (int m = 0; m < 8; ++m)
      #pragma unroll
      for (int n = 0; n < 4; ++n)
        acc[m][n] = __builtin_amdgcn_mfma_f32_16x16x32_bf16(af[m], bfv[n], acc[m][n], 0, 0, 0);
    __builtin_amdgcn_s_setprio(0);
    // retire this tile's ds_reads (HW) before crossing next barrier
    asm volatile("s_waitcnt lgkmcnt(0)" ::: "memory");
  }
}

#define ACC256_ZERO(acc) \
  _Pragma("unroll") for (int m_ = 0; m_ < 8; m_++) \
  _Pragma("unroll") for (int n_ = 0; n_ < 4; n_++) \
  _Pragma("unroll") for (int r_ = 0; r_ < 4; r_++) acc[m_][n_][r_] = 0.0f;

#define EPI256_BEGIN(acc) { \
  const int lane_ = threadIdx.x & 63; \
  const int wave_ = threadIdx.x >> 6; \
  const int wrb_ = (wave_ >> 2) * 128; \
  const int wnb_ = (wave_ & 3) * 64; \
  const int rb_ = (lane_ >> 4) << 2; \
  const int cb_ = lane_ & 15; \
  _Pragma("unroll") for (int m_ = 0; m_ < 8; m_++) \
  _Pragma("unroll") for (int n_ = 0; n_ < 4; n_++) \
  _Pragma("unroll") for (int r_ = 0; r_ < 4; r_++) { \
    const int rloc = wrb_ + m_ * 16 + rb_ + r_; \
    const int cloc = wnb_ + n_ * 16 + cb_; \
    const float aval = acc[m_][n_][r_];
#define EPI256_END() } }

// ---------------- 128x128 GEMM core (kept for scores/av) ----------------
__device__ __forceinline__ void gemm_core(
    const ushort* __restrict__ Ablk, int lda,
    const ushort* __restrict__ Bblk, int ldb,
    int k_begin, int k_end,
    ushort* __restrict__ As, ushort* __restrict__ Bs,
    f32x4 acc[4][4])
{
  const int tid  = threadIdx.x;
  const int lane = tid & 63;
  const int wr = ((tid >> 7) & 1) * 64;
  const int wc = ((tid >> 6) & 1) * 64;
  const int lr = lane & 15;
  const int ks = (lane >> 4) << 3;

  const int row0 = tid >> 2;
  const int row1 = 64 + row0;
  const int seg  = tid & 3;
  ushort* ldsA0 = As + (tid & 192) * 8;
  ushort* ldsA1 = As + (256 + (tid & 192)) * 8;
  ushort* ldsB0 = Bs + (tid & 192) * 8;
  ushort* ldsB1 = Bs + (256 + (tid & 192)) * 8;

  for (int k0 = k_begin; k0 < k_end; k0 += 32) {
    __syncthreads();
    gload16(Ablk + (size_t)row0 * lda + k0 + seg * 8, ldsA0);
    gload16(Ablk + (size_t)row1 * lda + k0 + seg * 8, ldsA1);
    gload16(Bblk + (size_t)row0 * ldb + k0 + seg * 8, ldsB0);
    gload16(Bblk + (size_t)row1 * ldb + k0 + seg * 8, ldsB1);
    asm volatile("s_waitcnt vmcnt(0)" ::: "memory");
    __syncthreads();

    bf16x8 af[4], bfv[4];
    #pragma unroll
    for (int m = 0; m < 4; m++)
      af[m] = *(const bf16x8*)(As + (wr + m * 16 + lr) * 32 + ks);
    #pragma unroll
    for (int n = 0; n < 4; n++)
      bfv[n] = *(const bf16x8*)(Bs + (wc + n * 16 + lr) * 32 + ks);
    #pragma unroll
    for (int m = 0; m < 4; m++)
      #pragma unroll
      for (int n = 0; n < 4; n++)
        acc[m][n] = __builtin_amdgcn_mfma_f32_16x16x32_bf16(af[m], bfv[n], acc[m][n], 0, 0, 0);
  }
}

#define ACC_ZERO(acc) \
  _Pragma("unroll") for (int m_ = 0; m_ < 4; m_++) \
  _Pragma("unroll") for (int n_ = 0; n_ < 4; n_++) \
  _Pragma("unroll") for (int r_ = 0; r_ < 4; r_++) acc[m_][n_][r_] = 0.0f;

#define EPI_BEGIN(acc) { \
  const int lane_ = threadIdx.x & 63; \
  const int wr_ = ((threadIdx.x >> 7) & 1) * 64; \
  const int wc_ = ((threadIdx.x >> 6) & 1) * 64; \
  const int rb_ = (lane_ >> 4) << 2; \
  const int cb_ = lane_ & 15; \
  _Pragma("unroll") for (int m_ = 0; m_ < 4; m_++) \
  _Pragma("unroll") for (int n_ = 0; n_ < 4; n_++) \
  _Pragma("unroll") for (int r_ = 0; r_ < 4; r_++) { \
    const int rloc = wr_ + m_ * 16 + rb_ + r_; \
    const int cloc = wc_ + n_ * 16 + cb_; \
    const float aval = acc[m_][n_][r_];
#define EPI_END() } }

// ---------------- elementwise prep kernels ----------------
__global__ __launch_bounds__(256) void prep_x(const float* __restrict__ x, ushort* __restrict__ xb) {
  size_t idx = ((size_t)blockIdx.x * 256 + threadIdx.x) * 4;   // dest flat index (b,s,d)
  int d = (int)(idx & 1023);
  int s = (int)((idx >> 10) & 4095);
  int b = (int)(idx >> 22);
  float4 v = *(const float4*)(x + ((size_t)s * BATCH + b) * DIM + d);
  ushort4 o;
  o.x = f2bf(v.x); o.y = f2bf(v.y); o.z = f2bf(v.z); o.w = f2bf(v.w);
  *(ushort4*)(xb + idx) = o;
}

__global__ __launch_bounds__(256) void f2bf_vec(const float* __restrict__ src, ushort* __restrict__ dst, int n) {
  int idx = (blockIdx.x * 256 + threadIdx.x) * 4;
  if (idx >= n) return;
  float4 v = *(const float4*)(src + idx);
  ushort4 o;
  o.x = f2bf(v.x); o.y = f2bf(v.y); o.z = f2bf(v.z); o.w = f2bf(v.w);
  *(ushort4*)(dst + idx) = o;
}

// ---------------- big GEMMs on the 256 core ----------------
// qkv: A = xb [16384 x 1024], B = wqkv [3072 x 1024] (rows = out cols, packed K;Q;V)
__global__ __launch_bounds__(512, 2) void qkv_gemm256(
    const ushort* __restrict__ xb, const ushort* __restrict__ wqkv,
    ushort* __restrict__ Kp, ushort* __restrict__ Qp, ushort* __restrict__ Vp)
{
  __shared__ ushort lds[65536];
  const int bx = blockIdx.x;   // 0..11
  const int by = blockIdx.y;   // 0..63
  f32x4 acc[8][4];
  ACC256_ZERO(acc)
  gemm256_core(xb + (size_t)by * 256 * DIM, DIM,
               wqkv + (size_t)bx * 256 * DIM, DIM, DIM, lds, acc);
  ushort* dst = (bx < 4) ? Kp : (bx < 8) ? Qp : Vp;
  const int colb = (bx & 3) * 256;
  EPI256_BEGIN(acc)
    int row = by * 256 + rloc;
    int col = colb + cloc;
    dst[(size_t)row * DIM + col] = f2bf(aval);
  EPI256_END()
}

__global__ __launch_bounds__(512, 2) void wp_gemm256(
    const ushort* __restrict__ cbuf, const ushort* __restrict__ wpb,
    const float* __restrict__ x, float* __restrict__ y0)
{
  __shared__ ushort lds[65536];
  const int bx = blockIdx.x;   // 0..3
  const int by = blockIdx.y;   // 0..63
  f32x4 acc[8][4];
  ACC256_ZERO(acc)
  gemm256_core(cbuf + (size_t)by * 256 * DIM, DIM,
               wpb + (size_t)bx * 256 * DIM, DIM, DIM, lds, acc);
  EPI256_BEGIN(acc)
    int row = by * 256 + rloc;           // b*4096+s
    int col = bx * 256 + cloc;
    int b = row >> 12, s = row & 4095;
    y0[(size_t)row * DIM + col] = aval + x[((size_t)s * BATCH + b) * DIM + col];
  EPI256_END()
}

__global__ __launch_bounds__(512, 2) void ffn1_gemm256(
    const ushort* __restrict__ y1, const ushort* __restrict__ w1b,
    const float* __restrict__ b1, float* __restrict__ h0)
{
  __shared__ ushort lds[65536];
  const int bx = blockIdx.x;   // 0..3
  const int by = blockIdx.y;   // 0..63
  f32x4 acc[8][4];
  ACC256_ZERO(acc)
  gemm256_core(y1 + (size_t)by * 256 * DIM, DIM,
               w1b + (size_t)bx * 256 * DIM, DIM, DIM, lds, acc);
  EPI256_BEGIN(acc)
    int row = by * 256 + rloc;
    int col = bx * 256 + cloc;
    h0[(size_t)row * DIM + col] = fmaxf(aval + b1[col], 0.0f);
  EPI256_END()
}

// ---------------- attention path (128 core) ----------------
__global__ __launch_bounds__(256) void transpose_v(const ushort* __restrict__ V, ushort* __restrict__ VT) {
  __shared__ ushort tile[64][66];
  const int s0 = blockIdx.x * 64, d0 = blockIdx.y * 64, b = blockIdx.z;
  const ushort* Vb = V + (size_t)b * S_LEN * DIM;
  ushort* VTb = VT + (size_t)b * DIM * S_LEN;
  #pragma unroll
  for (int it = 0; it < 16; it++) {
    int flat = it * 256 + threadIdx.x;
    int r = flat >> 6, c = flat & 63;
    tile[r][c] = Vb[(size_t)(s0 + r) * DIM + d0 + c];
  }
  __syncthreads();
  #pragma unroll
  for (int it = 0; it < 16; it++) {
    int flat = it * 256 + threadIdx.x;
    int r = flat >> 6, c = flat & 63;      // r = d-local, c = s-local
    VTb[(size_t)(d0 + r) * S_LEN + s0 + c] = tile[c][r];
  }
}

__global__ __launch_bounds__(256) void scores_gemm(
    const ushort* __restrict__ Qp, const ushort* __restrict__ Kp,
    float* __restrict__ eband)
{
  const int bid = blockIdx.x;        // 4*32*5 = 640
  const int b   = bid / 160;
  const int rem = bid % 160;
  const int i   = rem / 5;
  const int jj  = rem % 5;
  const int j   = i - 2 + jj;
  if (j < 0 || j >= NBLK) return;
  __shared__ ushort As[4096], Bs[4096];
  f32x4 acc[4][4];
  ACC_ZERO(acc)
  gemm_core(Qp + ((size_t)b * S_LEN + i * 128) * DIM, DIM,
            Kp + ((size_t)b * S_LEN + j * 128) * DIM, DIM, 0, DIM, As, Bs, acc);
  EPI_BEGIN(acc)
    int q = i * 128 + rloc;
    int k = j * 128 + cloc;
    float v = aval * SCALE;
    int dqk = q - k;
    if (dqk == 0 || dqk > AP || dqk < -AP) v = -INFINITY;
    eband[((size_t)b * S_LEN + q) * BANDC + jj * 128 + cloc] = v;
  EPI_END()
}

__global__ __launch_bounds__(256) void softmax_band(const float* __restrict__ eband,
                                                    ushort* __restrict__ aband)
{
  __shared__ float red[4];
  const int qg = blockIdx.x;          // 0..16383
  const int s  = qg & 4095;
  const int i  = s >> 7;
  const float* row = eband + (size_t)qg * BANDC;
  ushort* arow = aband + (size_t)qg * BANDC;

  float vals[3];
  bool  valid[3];
  float mx = -INFINITY;
  #pragma unroll
  for (int t = 0; t < 3; t++) {
    int idx = threadIdx.x + t * 256;
    int jj = idx >> 7;
    int j = i - 2 + jj;
    bool ok = (idx < BANDC) && (j >= 0) && (j < NBLK);
    valid[t] = ok;
    float v = ok ? row[idx] : -INFINITY;
    vals[t] = v;
    mx = fmaxf(mx, v);
  }
  float bmax = block_max(mx, red);
  float ss = 0.0f;
  #pragma unroll
  for (int t = 0; t < 3; t++) {
    float e = valid[t] ? __expf(vals[t] - bmax) : 0.0f;
    vals[t] = e;
    ss += e;
  }
  float inv = 1.0f / block_sum(ss, red);
  #pragma unroll
  for (int t = 0; t < 3; t++) {
    int idx = threadIdx.x + t * 256;
    if (idx < BANDC) arow[idx] = f2bf(vals[t] * inv);
  }
}

__global__ __launch_bounds__(256) void av_gemm(
    const ushort* __restrict__ aband, const ushort* __restrict__ VT,
    ushort* __restrict__ cbuf)
{
  const int by = blockIdx.y;          // 0..127: (b,i)
  const int b = by >> 5, i = by & 31;
  const int bx = blockIdx.x;          // 0..7 d-block
  const int jj_lo = (i < 2) ? (2 - i) : 0;
  const int jj_hi = (i > 29) ? (34 - i) : 5;
  __shared__ ushort As[4096], Bs[4096];
  f32x4 acc[4][4];
  ACC_ZERO(acc)
  const ushort* Ablk = aband + ((size_t)b * S_LEN + i * 128) * BANDC;
  const ushort* Bblk = VT + (size_t)b * DIM * S_LEN + (size_t)bx * 128 * S_LEN + (i - 2) * 128;
  gemm_core(Ablk, BANDC, Bblk, S_LEN, jj_lo * 128, jj_hi * 128, As, Bs, acc);
  EPI_BEGIN(acc)
    int row = b * S_LEN + i * 128 + rloc;
    int col = bx * 128 + cloc;
    cbuf[(size_t)row * DIM + col] = f2bf(aval);
  EPI_END()
}

// ---------------- norm / head ----------------
__global__ __launch_bounds__(256) void ln_kernel(const float* __restrict__ y0, ushort* __restrict__ y1,
                                                 const float* __restrict__ gamma, const float* __restrict__ beta)
{
  __shared__ float red[4];
  const size_t q = blockIdx.x;
  const float* row = y0 + q * DIM;
  float v[4];
  #pragma unroll
  for (int t = 0; t < 4; t++) v[t] = row[threadIdx.x + t * 256];
  float mean = block_sum(v[0] + v[1] + v[2] + v[3], red) * (1.0f / DIM);
  float q2 = 0.0f;
  #pragma unroll
  for (int t = 0; t < 4; t++) { float d = v[t] - mean; q2 += d * d; }
  float var = block_sum(q2, red) * (1.0f / DIM);
  float rstd = rsqrtf(var + 1e-6f);
  #pragma unroll
  for (int t = 0; t < 4; t++) {
    int d = threadIdx.x + t * 256;
    y1[q * DIM + d] = f2bf((v[t] - mean) * rstd * gamma[d] + beta[d]);
  }
}

__global__ __launch_bounds__(256) void head_kernel(const float* __restrict__ h0,
    const float* __restrict__ gamma, const float* __restrict__ beta,
    const float* __restrict__ W2, const float* __restrict__ b2,
    float* __restrict__ out)
{
  __shared__ float red[4];
  const int qg = blockIdx.x;
  const int b = qg >> 12, s = qg & 4095;
  const float* row = h0 + (size_t)qg * DIM;
  float v[4];
  #pragma unroll
  for (int t = 0; t < 4; t++) v[t] = row[threadIdx.x + t * 256];
  float mean = block_sum(v[0] + v[1] + v[2] + v[3], red) * (1.0f / DIM);
  float q2 = 0.0f;
  #pragma unroll
  for (int t = 0; t < 4; t++) { float d = v[t] - mean; q2 += d * d; }
  float var = block_sum(q2, red) * (1.0f / DIM);
  float rstd = rsqrtf(var + 1e-6f);
  float part = 0.0f;
  #pragma unroll
  for (int t = 0; t < 4; t++) {
    int d = threadIdx.x + t * 256;
    part += ((v[t] - mean) * rstd * gamma[d] + beta[d]) * W2[d];
  }
  float logit = block_sum(part, red) + b2[0];
  if (threadIdx.x == 0) out[(size_t)s * BATCH + b] = 1.0f / (1.0f + expf(-logit));
}

// ---------------- launch ----------------
extern "C" void kernel_launch(void* const* d_in, const int* in_sizes, int n_in,
                              void* d_out, int out_size, void* d_ws, size_t ws_size,
                              hipStream_t stream) {
  const float* x     = (const float*)d_in[0];
  const float* Wk    = (const float*)d_in[1];
  const float* Wq    = (const float*)d_in[2];
  const float* Wv    = (const float*)d_in[3];
  const float* Wp    = (const float*)d_in[4];
  const float* W1    = (const float*)d_in[5];
  const float* b1    = (const float*)d_in[6];
  const float* W2    = (const float*)d_in[7];
  const float* b2    = (const float*)d_in[8];
  const float* gamma = (const float*)d_in[9];
  const float* beta  = (const float*)d_in[10];
  float* out = (float*)d_out;

  char* w = (char*)d_ws;
  ushort* xb   = (ushort*)(w + 0);            // 33,554,432 B
  ushort* wqkv = (ushort*)(w + 33554432);     //  6,291,456 B
  ushort* wpb  = (ushort*)(w + 39845888);     //  2,097,152 B
  ushort* w1b  = (ushort*)(w + 41943040);     //  2,097,152 B
  ushort* Qp   = (ushort*)(w + 44040192);     // 33,554,432 B
  ushort* Kp   = (ushort*)(w + 77594624);     // 33,554,432 B
  ushort* Vp   = (ushort*)(w + 111149056);    // 33,554,432 B
  ushort* VT   = (ushort*)(w + 144703488);    // 33,554,432 B
  float*  big  = (float*)(w + 178257920);     // 67,108,864 B (eband -> y0 -> h0)
  // reuse (sequentially dead regions):
  ushort* aband = Qp;     // Q dead after scores
  ushort* cbuf  = Kp;     // K dead after scores
  ushort* y1    = Vp;     // V dead after transpose
  float* eband = big;
  float* y0    = big;
  float* h0    = big;

  prep_x<<<16384, 256, 0, stream>>>(x, xb);
  f2bf_vec<<<1024, 256, 0, stream>>>(Wk, wqkv,            1048576);
  f2bf_vec<<<1024, 256, 0, stream>>>(Wq, wqkv + 1048576,  1048576);
  f2bf_vec<<<1024, 256, 0, stream>>>(Wv, wqkv + 2097152,  1048576);
  f2bf_vec<<<1024, 256, 0, stream>>>(Wp, wpb, 1048576);
  f2bf_vec<<<1024, 256, 0, stream>>>(W1, w1b, 1048576);

  qkv_gemm256<<<dim3(12, 64), 512, 0, stream>>>(xb, wqkv, Kp, Qp, Vp);
  transpose_v<<<dim3(64, 16, 4), 256, 0, stream>>>(Vp, VT);
  scores_gemm<<<640, 256, 0, stream>>>(Qp, Kp, eband);
  softmax_band<<<16384, 256, 0, stream>>>(eband, aband);
  av_gemm<<<dim3(8, 128), 256, 0, stream>>>(aband, VT, cbuf);
  wp_gemm256<<<dim3(4, 64), 512, 0, stream>>>(cbuf, wpb, x, y0);
  ln_kernel<<<16384, 256, 0, stream>>>(y0, y1, gamma, beta);
  ffn1_gemm256<<<dim3(4, 64), 512, 0, stream>>>(y1, w1b, b1, h0);
  head_kernel<<<16384, 256, 0, stream>>>(h0, gamma, beta, W2, b2, out);
}